// Round 12
// baseline (2937.051 us; speedup 1.0000x reference)
//
#include <hip/hip_runtime.h>

#define NSAMP 32768
#define INB   4
#define HIDN  4
#define CHN   2
#define OUTD  10
#define NPIX  196
#define NPAIR 97             /* 194 middle BN steps, processed 2 per grid sync */
#define BLK   512
#define NBLK  (NSAMP / BLK)  /* 64 blocks, 1 sample per thread */
#define NCOMP 192            /* 184 moment comps + 8 pad */
#define INV_ROWS 1.52587890625e-05f   /* 1/(N*CH) = 1/65536 */
#define BN_EPS 1e-5f
#define SENTW 0xFFFFFFFFu    /* negative-NaN sentinel, unreachable by finite math */
/* ws: pay[NPAIR][NBLK][NCOMP] f32, relaxed agent u32 stores; merged sentinel-
   gather (per-word check -> word atomicity suffices). No atomics, deterministic. */
#define WS_BYTES ((size_t)NPAIR * NBLK * NCOMP * 4)

/* Moment layout:
   0-3 S1[h] | 4-7 S2[h] | 8-23 A[h][hp]=Σ u_h Mp_h,hp | 24-39 B[h][hp]=Σ Mp_h,hp
   40-79 C[p][hp]=Σ u_h u_g Mp_h Mp_g (sym pairs) | 80-143 D[h][g][hp]=Σ u_h Mp_h Mp_g
   144-183 E[p][hp]=Σ Mp_h Mp_g | 184-191 pad */

__device__ __forceinline__ float comp_val(const int k, const float u[CHN][4],
                                          const float Mp[CHN][4][4]) {
    constexpr int ph[10] = {0,0,0,0,1,1,1,2,2,3};
    constexpr int pg[10] = {0,1,2,3,1,2,3,2,3,3};
    float s = 0.f;
    if (k < 4) {
#pragma unroll
        for (int c = 0; c < CHN; ++c) s += u[c][k];
    } else if (k < 8) {
        const int h = k - 4;
#pragma unroll
        for (int c = 0; c < CHN; ++c) s = fmaf(u[c][h], u[c][h], s);
    } else if (k < 24) {
        const int h = (k - 8) >> 2, hp = k & 3;
#pragma unroll
        for (int c = 0; c < CHN; ++c) s = fmaf(u[c][h], Mp[c][h][hp], s);
    } else if (k < 40) {
        const int h = (k - 24) >> 2, hp = k & 3;
#pragma unroll
        for (int c = 0; c < CHN; ++c) s += Mp[c][h][hp];
    } else if (k < 80) {
        const int p = (k - 40) >> 2, hp = k & 3, h = ph[p], g = pg[p];
#pragma unroll
        for (int c = 0; c < CHN; ++c)
            s = fmaf(u[c][h] * u[c][g], Mp[c][h][hp] * Mp[c][g][hp], s);
    } else if (k < 144) {
        const int idx = k - 80, h = idx >> 4, g = (idx >> 2) & 3, hp = k & 3;
#pragma unroll
        for (int c = 0; c < CHN; ++c)
            s = fmaf(u[c][h], Mp[c][h][hp] * Mp[c][g][hp], s);
    } else if (k < 184) {
        const int p = (k - 144) >> 2, hp = k & 3, h = ph[p], g = pg[p];
#pragma unroll
        for (int c = 0; c < CHN; ++c) s = fmaf(Mp[c][h][hp], Mp[c][g][hp], s);
    }
    return s;
}

/* Reduce over 64 lanes of 32 per-lane partials; lane ln ends holding the
   wave-total of comp (ln&31). Peak live set: 32 regs. */
__device__ __forceinline__ float scatter32(float v[32], int ln) {
#pragma unroll
    for (int j = 0; j < 32; ++j) v[j] += __shfl_xor(v[j], 32);
#pragma unroll
    for (int b = 0; b < 5; ++b) {
        const int d = 1 << b;
        const bool hi = (ln >> b) & 1;
#pragma unroll
        for (int j = 0; j < (32 >> (b + 1)); ++j) {
            float keep = hi ? v[2 * j + 1] : v[2 * j];
            float send = hi ? v[2 * j]     : v[2 * j + 1];
            v[j] = keep + __shfl_xor(send, d);
        }
    }
    return v[0];
}

/* One bank: compute 32 comps + reduce-scatter. Template B keeps every index
   compile-time (no dynamic register indexing -> no scratch). */
template <int B>
__device__ __forceinline__ float bank_compute(const float u[CHN][4],
                                              const float Mp[CHN][4][4], int ln) {
    float v[32];
#pragma unroll
    for (int q = 0; q < 32; ++q) v[q] = comp_val(B * 32 + q, u, Mp);
    return scatter32(v, ln);
}

__global__ __launch_bounds__(BLK, 1)
void ttbn_main(const float* __restrict__ x,  const float* __restrict__ wf,
               const float* __restrict__ wm, const float* __restrict__ wl,
               const float* __restrict__ gamma, const float* __restrict__ beta,
               float* __restrict__ out, float* __restrict__ ws)
{
    __shared__ float wb[8][6][32];     // per-wave scatter results
    __shared__ float sum2[2][NCOMP];   // gather halves
    __shared__ float tot[NCOMP];       // grid totals
    const int tid = threadIdx.x;
    const int ln  = tid & 63, wv = tid >> 6;
    const long n  = (long)blockIdx.x * BLK + tid;

    float gm[HIDN], bt[HIDN];
#pragma unroll
    for (int h = 0; h < HIDN; ++h) { gm[h] = gamma[h]; bt[h] = beta[h]; }

    const float* xrow = x + n * (INB * NPIX);

    // ---- pixel 0 (no BN) ----
    float y[CHN][HIDN];
    {
        float x0[INB];
#pragma unroll
        for (int i = 0; i < INB; ++i) x0[i] = xrow[i * NPIX];
#pragma unroll
        for (int c = 0; c < CHN; ++c)
#pragma unroll
            for (int h = 0; h < HIDN; ++h) {
                float acc = 0.f;
#pragma unroll
                for (int i = 0; i < INB; ++i)
                    acc = fmaf(x0[i], wf[(i * HIDN + h) * CHN + c], acc);
                y[c][h] = acc;
            }
    }
    float xa[INB], xb[INB];   // pair-0 pixels (1,2)
#pragma unroll
    for (int i = 0; i < INB; ++i) { xa[i] = xrow[i * NPIX + 1]; xb[i] = xrow[i * NPIX + 2]; }

#pragma unroll 1
    for (int j = 0; j < NPAIR; ++j) {
        const float* w0 = wm + (size_t)(2 * j) * 128;
        const float* w1 = w0 + 128;

        // u = y · M(xa,w0), M streamed (never materialized)
        float u[CHN][HIDN] = {{0.f,0.f,0.f,0.f},{0.f,0.f,0.f,0.f}};
#pragma unroll
        for (int r = 0; r < 4; ++r)
#pragma unroll
            for (int h = 0; h < 4; ++h)
#pragma unroll
                for (int c = 0; c < CHN; ++c) {
                    float m = 0.f;
#pragma unroll
                    for (int i = 0; i < INB; ++i)
                        m = fmaf(xa[i], w0[(r * 16 + i * 4 + h) * 2 + c], m);
                    u[c][h] = fmaf(y[c][r], m, u[c][h]);
                }
        // Mp(xb,w1)
        float Mp[CHN][4][4];
#pragma unroll
        for (int r = 0; r < 4; ++r)
#pragma unroll
            for (int h = 0; h < 4; ++h)
#pragma unroll
                for (int c = 0; c < CHN; ++c) {
                    float m = 0.f;
#pragma unroll
                    for (int i = 0; i < INB; ++i)
                        m = fmaf(xb[i], w1[(r * 16 + i * 4 + h) * 2 + c], m);
                    Mp[c][r][h] = m;
                }
        // prefetch next pair's pixels (in flight across banks + sync)
        float xa2[INB], xb2[INB];
        if (j < NPAIR - 1) {
#pragma unroll
            for (int i = 0; i < INB; ++i) {
                xa2[i] = xrow[i * NPIX + 2 * j + 3];
                xb2[i] = xrow[i * NPIX + 2 * j + 4];
            }
        }
        // ---- 6 banks, ROLLED loop + uniform branch dispatch: control flow
        //      stops the scheduler from interleaving banks -> one v[32] live ----
#pragma unroll 1
        for (int b = 0; b < 6; ++b) {
            float r;
            if      (b == 0) r = bank_compute<0>(u, Mp, ln);
            else if (b == 1) r = bank_compute<1>(u, Mp, ln);
            else if (b == 2) r = bank_compute<2>(u, Mp, ln);
            else if (b == 3) r = bank_compute<3>(u, Mp, ln);
            else if (b == 4) r = bank_compute<4>(u, Mp, ln);
            else             r = bank_compute<5>(u, Mp, ln);
            if (ln < 32) wb[wv][b][ln] = r;
        }
        __syncthreads();
        // cross-wave combine + payload store (192 threads)
        if (tid < NCOMP) {
            float s = 0.f;
#pragma unroll
            for (int w = 0; w < 8; ++w) s += wb[w][tid >> 5][tid & 31];
            __hip_atomic_store((unsigned*)ws + ((size_t)j * NBLK + blockIdx.x) * NCOMP + tid,
                               __float_as_uint(s), __ATOMIC_RELAXED, __HIP_MEMORY_SCOPE_AGENT);
        }
        // merged sentinel-gather: thread (half,k) sums comp k over 32 blocks.
        // unroll 8 caps the in-flight-load register burst (R9 used 32).
        if (tid < 2 * NCOMP) {
            const int half = tid >= NCOMP ? 1 : 0;
            const int k = tid - half * NCOMP;
            const unsigned* gp = (const unsigned*)ws + ((size_t)j * NBLK + half * 32) * NCOMP + k;
            float s; bool ok;
            do {
                ok = true; s = 0.f;
#pragma unroll 8
                for (int b = 0; b < 32; ++b) {
                    unsigned wd = __hip_atomic_load(gp + (size_t)b * NCOMP, __ATOMIC_RELAXED,
                                                    __HIP_MEMORY_SCOPE_AGENT);
                    ok = ok && (wd != SENTW);
                    s += __uint_as_float(wd);
                }
            } while (__any(!ok));
            sum2[half][k] = s;
        }
        __syncthreads();
        if (tid < NCOMP) tot[tid] = sum2[0][tid] + sum2[1][tid];
        __syncthreads();

        // ---- recombine BN coefs for both steps (redundant per thread) ----
        constexpr int ph[10] = {0,0,0,0,1,1,1,2,2,3};
        constexpr int pg[10] = {0,1,2,3,1,2,3,2,3,3};
        float is_[4], sh_[4];
#pragma unroll
        for (int h = 0; h < 4; ++h) {
            float m  = tot[h] * INV_ROWS;
            float va = fmaf(-m, m, tot[4 + h] * INV_ROWS);
            float r  = rsqrtf(va + BN_EPS) * gm[h];
            is_[h] = r; sh_[h] = bt[h] - m * r;
        }
        float is2[4], sh2[4];
#pragma unroll
        for (int hp = 0; hp < 4; ++hp) {
            float s1 = 0.f;
#pragma unroll
            for (int h = 0; h < 4; ++h) {
                s1 = fmaf(is_[h], tot[8  + h * 4 + hp], s1);
                s1 = fmaf(sh_[h], tot[24 + h * 4 + hp], s1);
            }
            float s2 = 0.f;
#pragma unroll
            for (int p = 0; p < 10; ++p) {
                const int h = ph[p], g = pg[p];
                const float f = (h == g) ? 1.f : 2.f;
                s2 = fmaf(f * is_[h] * is_[g], tot[40  + p * 4 + hp], s2);
                s2 = fmaf(f * sh_[h] * sh_[g], tot[144 + p * 4 + hp], s2);
            }
#pragma unroll
            for (int h = 0; h < 4; ++h)
#pragma unroll
                for (int g = 0; g < 4; ++g)
                    s2 = fmaf(2.f * is_[h] * sh_[g], tot[80 + (h * 4 + g) * 4 + hp], s2);
            float m2  = s1 * INV_ROWS;
            float va2 = fmaf(-m2, m2, s2 * INV_ROWS);
            float r2  = rsqrtf(va2 + BN_EPS) * gm[hp];
            is2[hp] = r2; sh2[hp] = bt[hp] - m2 * r2;
        }
        // ---- advance state through both steps ----
#pragma unroll
        for (int c = 0; c < CHN; ++c) {
            float yp[4];
#pragma unroll
            for (int h = 0; h < 4; ++h) yp[h] = fmaf(u[c][h], is_[h], sh_[h]);
#pragma unroll
            for (int hp = 0; hp < 4; ++hp) {
                float up = 0.f;
#pragma unroll
                for (int h = 0; h < 4; ++h) up = fmaf(yp[h], Mp[c][h][hp], up);
                y[c][hp] = fmaf(up, is2[hp], sh2[hp]);
            }
        }
        if (j < NPAIR - 1) {
#pragma unroll
            for (int i = 0; i < INB; ++i) { xa[i] = xa2[i]; xb[i] = xb2[i]; }
        }
    }

    // ---- final step: pixel 195 with wl, no BN ----
    {
        float xv[INB];
#pragma unroll
        for (int i = 0; i < INB; ++i) xv[i] = xrow[i * NPIX + 195];
        float o0[OUTD], o1[OUTD];
#pragma unroll
        for (int od = 0; od < OUTD; ++od) { o0[od] = 0.f; o1[od] = 0.f; }
#pragma unroll
        for (int r = 0; r < 4; ++r)
#pragma unroll
            for (int i = 0; i < INB; ++i) {
                float p0 = y[0][r] * xv[i];
                float p1 = y[1][r] * xv[i];
                const float* wri = wl + r * (INB * OUTD * CHN) + i * (OUTD * CHN);
#pragma unroll
                for (int od = 0; od < OUTD; ++od) {
                    o0[od] = fmaf(p0, wri[od * CHN + 0], o0[od]);
                    o1[od] = fmaf(p1, wri[od * CHN + 1], o1[od]);
                }
            }
        float tmp[20];
#pragma unroll
        for (int od = 0; od < OUTD; ++od) { tmp[od] = o0[od]; tmp[10 + od] = o1[od]; }
        float4* o4 = reinterpret_cast<float4*>(out + n * (CHN * OUTD));
#pragma unroll
        for (int q = 0; q < 5; ++q)
            o4[q] = make_float4(tmp[q * 4], tmp[q * 4 + 1], tmp[q * 4 + 2], tmp[q * 4 + 3]);
    }
}

extern "C" void kernel_launch(void* const* d_in, const int* in_sizes, int n_in,
                              void* d_out, int out_size, void* d_ws, size_t ws_size,
                              hipStream_t stream) {
    const float* x     = (const float*)d_in[0];
    const float* wf    = (const float*)d_in[1];
    const float* wm    = (const float*)d_in[2];
    const float* wl    = (const float*)d_in[3];
    const float* gamma = (const float*)d_in[4];
    const float* beta  = (const float*)d_in[5];
    float*       out   = (float*)d_out;
    float*       ws    = (float*)d_ws;

    // sentinel-fill payload area (0xFF bytes == SENTW in every word)
    hipMemsetAsync(d_ws, 0xFF, WS_BYTES, stream);

    void* args[] = { &x, &wf, &wm, &wl, &gamma, &beta, &out, &ws };
    hipLaunchCooperativeKernel((void*)ttbn_main, dim3(NBLK), dim3(BLK),
                               args, 0, stream);
}

// Round 13
// 2828.745 us; speedup vs baseline: 1.0383x; 1.0383x over previous
//
#include <hip/hip_runtime.h>

#define NSAMP 32768
#define INB   4
#define HIDN  4
#define CHN   2
#define OUTD  10
#define NPIX  196
#define NPAIR 97             /* 194 middle BN steps, processed 2 per grid sync */
#define BLK   512
#define NBLK  (NSAMP / BLK)  /* 64 blocks, 1 sample per thread */
#define NCOMP 192            /* 184 moment comps + 8 pad */
#define NBANK 12             /* 12 banks x 16 comps */
#define INV_ROWS 1.52587890625e-05f   /* 1/(N*CH) = 1/65536 */
#define BN_EPS 1e-5f
#define SENTW 0xFFFFFFFFu    /* negative-NaN sentinel, unreachable by finite math */
#define WS_BYTES ((size_t)NPAIR * NBLK * NCOMP * 4)

/* Moment layout:
   0-3 S1[h] | 4-7 S2[h] | 8-23 A[h][hp]=Σ u_h Mp_h,hp | 24-39 B[h][hp]=Σ Mp_h,hp
   40-79 C[p][hp]=Σ u_h u_g Mp_h Mp_g (sym pairs) | 80-143 D[h][g][hp]=Σ u_h Mp_h Mp_g
   144-183 E[p][hp]=Σ Mp_h Mp_g | 184-191 pad */

__device__ __forceinline__ float comp_val(const int k, const float u[CHN][4],
                                          const float Mp[CHN][4][4]) {
    constexpr int ph[10] = {0,0,0,0,1,1,1,2,2,3};
    constexpr int pg[10] = {0,1,2,3,1,2,3,2,3,3};
    float s = 0.f;
    if (k < 4) {
#pragma unroll
        for (int c = 0; c < CHN; ++c) s += u[c][k];
    } else if (k < 8) {
        const int h = k - 4;
#pragma unroll
        for (int c = 0; c < CHN; ++c) s = fmaf(u[c][h], u[c][h], s);
    } else if (k < 24) {
        const int h = (k - 8) >> 2, hp = k & 3;
#pragma unroll
        for (int c = 0; c < CHN; ++c) s = fmaf(u[c][h], Mp[c][h][hp], s);
    } else if (k < 40) {
        const int h = (k - 24) >> 2, hp = k & 3;
#pragma unroll
        for (int c = 0; c < CHN; ++c) s += Mp[c][h][hp];
    } else if (k < 80) {
        const int p = (k - 40) >> 2, hp = k & 3, h = ph[p], g = pg[p];
#pragma unroll
        for (int c = 0; c < CHN; ++c)
            s = fmaf(u[c][h] * u[c][g], Mp[c][h][hp] * Mp[c][g][hp], s);
    } else if (k < 144) {
        const int idx = k - 80, h = idx >> 4, g = (idx >> 2) & 3, hp = k & 3;
#pragma unroll
        for (int c = 0; c < CHN; ++c)
            s = fmaf(u[c][h], Mp[c][h][hp] * Mp[c][g][hp], s);
    } else if (k < 184) {
        const int p = (k - 144) >> 2, hp = k & 3, h = ph[p], g = pg[p];
#pragma unroll
        for (int c = 0; c < CHN; ++c) s = fmaf(Mp[c][h][hp], Mp[c][g][hp], s);
    }
    return s;
}

/* Fold 64 lanes -> 16-lane groups, then 4-stage reduce-scatter: lane ln ends
   holding the wave-total of comp (ln & 15). Peak live: 16 regs. */
__device__ __forceinline__ float scatter16(float v[16], int ln) {
#pragma unroll
    for (int j = 0; j < 16; ++j) {
        v[j] += __shfl_xor(v[j], 32);
        v[j] += __shfl_xor(v[j], 16);
    }
#pragma unroll
    for (int b = 0; b < 4; ++b) {
        const int d = 1 << b;
        const bool hi = (ln >> b) & 1;
#pragma unroll
        for (int j = 0; j < (16 >> (b + 1)); ++j) {
            float keep = hi ? v[2 * j + 1] : v[2 * j];
            float send = hi ? v[2 * j]     : v[2 * j + 1];
            v[j] = keep + __shfl_xor(send, d);
        }
    }
    return v[0];
}

template <int B>
__device__ __forceinline__ float bank_compute(const float u[CHN][4],
                                              const float Mp[CHN][4][4], int ln) {
    float v[16];
#pragma unroll
    for (int q = 0; q < 16; ++q) v[q] = comp_val(B * 16 + q, u, Mp);
    return scatter16(v, ln);
}

/* Volatile register pin: redefines u/Mp so the next bank's FMAs depend on it;
   volatile asms keep program order among themselves -> banks are serialized in
   the DEPENDENCE GRAPH (if-conversion/scheduler cannot overlap them). */
__device__ __forceinline__ void pin_state(float u[CHN][4], float Mp[CHN][4][4]) {
    asm volatile("" :
      "+v"(u[0][0]), "+v"(u[0][1]), "+v"(u[0][2]), "+v"(u[0][3]),
      "+v"(u[1][0]), "+v"(u[1][1]), "+v"(u[1][2]), "+v"(u[1][3]),
      "+v"(Mp[0][0][0]), "+v"(Mp[0][0][1]), "+v"(Mp[0][0][2]), "+v"(Mp[0][0][3]),
      "+v"(Mp[0][1][0]), "+v"(Mp[0][1][1]), "+v"(Mp[0][1][2]), "+v"(Mp[0][1][3]),
      "+v"(Mp[0][2][0]), "+v"(Mp[0][2][1]), "+v"(Mp[0][2][2]), "+v"(Mp[0][2][3]),
      "+v"(Mp[0][3][0]), "+v"(Mp[0][3][1]), "+v"(Mp[0][3][2]), "+v"(Mp[0][3][3]));
    asm volatile("" :
      "+v"(Mp[1][0][0]), "+v"(Mp[1][0][1]), "+v"(Mp[1][0][2]), "+v"(Mp[1][0][3]),
      "+v"(Mp[1][1][0]), "+v"(Mp[1][1][1]), "+v"(Mp[1][1][2]), "+v"(Mp[1][1][3]),
      "+v"(Mp[1][2][0]), "+v"(Mp[1][2][1]), "+v"(Mp[1][2][2]), "+v"(Mp[1][2][3]),
      "+v"(Mp[1][3][0]), "+v"(Mp[1][3][1]), "+v"(Mp[1][3][2]), "+v"(Mp[1][3][3]));
}

__global__ __launch_bounds__(BLK, 1)
void ttbn_main(const float* __restrict__ x,  const float* __restrict__ wf,
               const float* __restrict__ wm, const float* __restrict__ wl,
               const float* __restrict__ gamma, const float* __restrict__ beta,
               float* __restrict__ out, float* __restrict__ ws)
{
    __shared__ float wb[8][NBANK][16];  // per-wave scatter results
    __shared__ float sum2[2][NCOMP];    // gather halves
    __shared__ float tot[NCOMP];        // grid totals
    const int tid = threadIdx.x;
    const int ln  = tid & 63, wv = tid >> 6;
    const long n  = (long)blockIdx.x * BLK + tid;

    float gm[HIDN], bt[HIDN];
#pragma unroll
    for (int h = 0; h < HIDN; ++h) { gm[h] = gamma[h]; bt[h] = beta[h]; }

    const float* xrow = x + n * (INB * NPIX);

    // ---- pixel 0 (no BN) ----
    float y[CHN][HIDN];
    {
        float x0[INB];
#pragma unroll
        for (int i = 0; i < INB; ++i) x0[i] = xrow[i * NPIX];
#pragma unroll
        for (int c = 0; c < CHN; ++c)
#pragma unroll
            for (int h = 0; h < HIDN; ++h) {
                float acc = 0.f;
#pragma unroll
                for (int i = 0; i < INB; ++i)
                    acc = fmaf(x0[i], wf[(i * HIDN + h) * CHN + c], acc);
                y[c][h] = acc;
            }
    }
    float xa[INB], xb[INB];   // pair-0 pixels (1,2)
#pragma unroll
    for (int i = 0; i < INB; ++i) { xa[i] = xrow[i * NPIX + 1]; xb[i] = xrow[i * NPIX + 2]; }

#pragma unroll 1
    for (int j = 0; j < NPAIR; ++j) {
        const float* w0 = wm + (size_t)(2 * j) * 128;
        const float* w1 = w0 + 128;

        // u = y · M(xa,w0), M streamed (never materialized)
        float u[CHN][HIDN] = {{0.f,0.f,0.f,0.f},{0.f,0.f,0.f,0.f}};
#pragma unroll
        for (int r = 0; r < 4; ++r)
#pragma unroll
            for (int h = 0; h < 4; ++h)
#pragma unroll
                for (int c = 0; c < CHN; ++c) {
                    float m = 0.f;
#pragma unroll
                    for (int i = 0; i < INB; ++i)
                        m = fmaf(xa[i], w0[(r * 16 + i * 4 + h) * 2 + c], m);
                    u[c][h] = fmaf(y[c][r], m, u[c][h]);
                }
        // Mp(xb,w1)
        float Mp[CHN][4][4];
#pragma unroll
        for (int r = 0; r < 4; ++r)
#pragma unroll
            for (int h = 0; h < 4; ++h)
#pragma unroll
                for (int c = 0; c < CHN; ++c) {
                    float m = 0.f;
#pragma unroll
                    for (int i = 0; i < INB; ++i)
                        m = fmaf(xb[i], w1[(r * 16 + i * 4 + h) * 2 + c], m);
                    Mp[c][r][h] = m;
                }
        // prefetch next pair's pixels
        float xa2[INB], xb2[INB];
        if (j < NPAIR - 1) {
#pragma unroll
            for (int i = 0; i < INB; ++i) {
                xa2[i] = xrow[i * NPIX + 2 * j + 3];
                xb2[i] = xrow[i * NPIX + 2 * j + 4];
            }
        }
        // ---- 12 banks of 16 comps, serialized by the volatile pin spine ----
        {
            float r;
#define DO_BANK(B)                                                 \
            r = bank_compute<B>(u, Mp, ln);                        \
            asm volatile("" : "+v"(r));                            \
            if (ln < 16) wb[wv][B][ln] = r;                        \
            pin_state(u, Mp);
            DO_BANK(0)  DO_BANK(1)  DO_BANK(2)  DO_BANK(3)
            DO_BANK(4)  DO_BANK(5)  DO_BANK(6)  DO_BANK(7)
            DO_BANK(8)  DO_BANK(9)  DO_BANK(10) DO_BANK(11)
#undef DO_BANK
        }
        __syncthreads();
        // cross-wave combine + payload store (192 threads)
        if (tid < NCOMP) {
            float s = 0.f;
#pragma unroll
            for (int w = 0; w < 8; ++w) s += wb[w][tid >> 4][tid & 15];
            __hip_atomic_store((unsigned*)ws + ((size_t)j * NBLK + blockIdx.x) * NCOMP + tid,
                               __float_as_uint(s), __ATOMIC_RELAXED, __HIP_MEMORY_SCOPE_AGENT);
        }
        // merged sentinel-gather: thread (half,k) sums comp k over 32 blocks
        if (tid < 2 * NCOMP) {
            const int half = tid >= NCOMP ? 1 : 0;
            const int k = tid - half * NCOMP;
            const unsigned* gp = (const unsigned*)ws + ((size_t)j * NBLK + half * 32) * NCOMP + k;
            float s; bool ok;
            do {
                ok = true; s = 0.f;
#pragma unroll 8
                for (int b = 0; b < 32; ++b) {
                    unsigned wd = __hip_atomic_load(gp + (size_t)b * NCOMP, __ATOMIC_RELAXED,
                                                    __HIP_MEMORY_SCOPE_AGENT);
                    ok = ok && (wd != SENTW);
                    s += __uint_as_float(wd);
                }
            } while (__any(!ok));
            sum2[half][k] = s;
        }
        __syncthreads();
        if (tid < NCOMP) tot[tid] = sum2[0][tid] + sum2[1][tid];
        __syncthreads();

        // ---- recombine BN coefs for both steps (redundant per thread) ----
        constexpr int ph[10] = {0,0,0,0,1,1,1,2,2,3};
        constexpr int pg[10] = {0,1,2,3,1,2,3,2,3,3};
        float is_[4], sh_[4];
#pragma unroll
        for (int h = 0; h < 4; ++h) {
            float m  = tot[h] * INV_ROWS;
            float va = fmaf(-m, m, tot[4 + h] * INV_ROWS);
            float r  = rsqrtf(va + BN_EPS) * gm[h];
            is_[h] = r; sh_[h] = bt[h] - m * r;
        }
        float is2[4], sh2[4];
#pragma unroll
        for (int hp = 0; hp < 4; ++hp) {
            float s1 = 0.f;
#pragma unroll
            for (int h = 0; h < 4; ++h) {
                s1 = fmaf(is_[h], tot[8  + h * 4 + hp], s1);
                s1 = fmaf(sh_[h], tot[24 + h * 4 + hp], s1);
            }
            float s2 = 0.f;
#pragma unroll
            for (int p = 0; p < 10; ++p) {
                const int h = ph[p], g = pg[p];
                const float f = (h == g) ? 1.f : 2.f;
                s2 = fmaf(f * is_[h] * is_[g], tot[40  + p * 4 + hp], s2);
                s2 = fmaf(f * sh_[h] * sh_[g], tot[144 + p * 4 + hp], s2);
            }
#pragma unroll
            for (int h = 0; h < 4; ++h)
#pragma unroll
                for (int g = 0; g < 4; ++g)
                    s2 = fmaf(2.f * is_[h] * sh_[g], tot[80 + (h * 4 + g) * 4 + hp], s2);
            float m2  = s1 * INV_ROWS;
            float va2 = fmaf(-m2, m2, s2 * INV_ROWS);
            float r2  = rsqrtf(va2 + BN_EPS) * gm[hp];
            is2[hp] = r2; sh2[hp] = bt[hp] - m2 * r2;
        }
        // ---- advance state through both steps ----
#pragma unroll
        for (int c = 0; c < CHN; ++c) {
            float yp[4];
#pragma unroll
            for (int h = 0; h < 4; ++h) yp[h] = fmaf(u[c][h], is_[h], sh_[h]);
#pragma unroll
            for (int hp = 0; hp < 4; ++hp) {
                float up = 0.f;
#pragma unroll
                for (int h = 0; h < 4; ++h) up = fmaf(yp[h], Mp[c][h][hp], up);
                y[c][hp] = fmaf(up, is2[hp], sh2[hp]);
            }
        }
        if (j < NPAIR - 1) {
#pragma unroll
            for (int i = 0; i < INB; ++i) { xa[i] = xa2[i]; xb[i] = xb2[i]; }
        }
    }

    // ---- final step: pixel 195 with wl, no BN ----
    {
        float xv[INB];
#pragma unroll
        for (int i = 0; i < INB; ++i) xv[i] = xrow[i * NPIX + 195];
        float o0[OUTD], o1[OUTD];
#pragma unroll
        for (int od = 0; od < OUTD; ++od) { o0[od] = 0.f; o1[od] = 0.f; }
#pragma unroll
        for (int r = 0; r < 4; ++r)
#pragma unroll
            for (int i = 0; i < INB; ++i) {
                float p0 = y[0][r] * xv[i];
                float p1 = y[1][r] * xv[i];
                const float* wri = wl + r * (INB * OUTD * CHN) + i * (OUTD * CHN);
#pragma unroll
                for (int od = 0; od < OUTD; ++od) {
                    o0[od] = fmaf(p0, wri[od * CHN + 0], o0[od]);
                    o1[od] = fmaf(p1, wri[od * CHN + 1], o1[od]);
                }
            }
        float tmp[20];
#pragma unroll
        for (int od = 0; od < OUTD; ++od) { tmp[od] = o0[od]; tmp[10 + od] = o1[od]; }
        float4* o4 = reinterpret_cast<float4*>(out + n * (CHN * OUTD));
#pragma unroll
        for (int q = 0; q < 5; ++q)
            o4[q] = make_float4(tmp[q * 4], tmp[q * 4 + 1], tmp[q * 4 + 2], tmp[q * 4 + 3]);
    }
}

extern "C" void kernel_launch(void* const* d_in, const int* in_sizes, int n_in,
                              void* d_out, int out_size, void* d_ws, size_t ws_size,
                              hipStream_t stream) {
    const float* x     = (const float*)d_in[0];
    const float* wf    = (const float*)d_in[1];
    const float* wm    = (const float*)d_in[2];
    const float* wl    = (const float*)d_in[3];
    const float* gamma = (const float*)d_in[4];
    const float* beta  = (const float*)d_in[5];
    float*       out   = (float*)d_out;
    float*       ws    = (float*)d_ws;

    // sentinel-fill payload area (0xFF bytes == SENTW in every word)
    hipMemsetAsync(d_ws, 0xFF, WS_BYTES, stream);

    void* args[] = { &x, &wf, &wm, &wl, &gamma, &beta, &out, &ws };
    hipLaunchCooperativeKernel((void*)ttbn_main, dim3(NBLK), dim3(BLK),
                               args, 0, stream);
}

// Round 14
// 1101.039 us; speedup vs baseline: 2.6675x; 2.5692x over previous
//
#include <hip/hip_runtime.h>

#define NSAMP 32768
#define INB   4
#define HIDN  4
#define CHN   2
#define OUTD  10
#define NPIX  196
#define NMID  194
#define BLK   256
#define SPT   4                        /* samples per thread */
#define NBLK  (NSAMP / (BLK * SPT))    /* 32 blocks */
#define INV_ROWS 1.52587890625e-05f    /* 1 / (N*CH) = 1/65536 */
#define BN_EPS 1e-5f
#define SENT  0xFFFFFFFFFFFFFFFFull    /* NaN-pair sentinel, unreachable by finite math */
/* ws: slots[NMID][NBLK][4] u64. 32 writers -> 128 u64 words per step; the
   polling wave reads words ln and ln+64 (two coalesced loads), so detection
   == data delivery over ALL writers in one shot, and the cross-block sum is
   a 4-stage butterfly of 2 floats. Wave 0 only (R8's fan-out fix). */
#define WS_BYTES ((size_t)NMID * NBLK * 4 * sizeof(unsigned long long))

__device__ __forceinline__ void mid_step(
    int t, const float xv[SPT][INB], float y[SPT][CHN][HIDN],
    const float* __restrict__ wm,
    const float gm[HIDN], const float bt[HIDN],
    unsigned long long* __restrict__ slots,
    float (*pb)[8], float* totl, int tid)
{
    const float* w = wm + (long)t * 128;   // 128 floats, wave-uniform
    float yn[SPT][CHN][HIDN];
#pragma unroll
    for (int s = 0; s < SPT; ++s)
#pragma unroll
        for (int c = 0; c < CHN; ++c)
#pragma unroll
            for (int h = 0; h < HIDN; ++h) yn[s][c][h] = 0.f;

#pragma unroll
    for (int s = 0; s < SPT; ++s)
#pragma unroll
        for (int r = 0; r < HIDN; ++r)
#pragma unroll
            for (int i = 0; i < INB; ++i) {
                float p0 = y[s][0][r] * xv[s][i];
                float p1 = y[s][1][r] * xv[s][i];
                const float* wri = w + r * (INB * HIDN * CHN) + i * (HIDN * CHN);
#pragma unroll
                for (int h = 0; h < HIDN; ++h) {
                    yn[s][0][h] = fmaf(p0, wri[h * CHN + 0], yn[s][0][h]);
                    yn[s][1][h] = fmaf(p1, wri[h * CHN + 1], yn[s][1][h]);
                }
            }
    // per-thread partials: sum / sumsq per h over samples+channels
    float red[8];
#pragma unroll
    for (int h = 0; h < HIDN; ++h) {
        float sm = 0.f, sq = 0.f;
#pragma unroll
        for (int s = 0; s < SPT; ++s) {
            sm += yn[s][0][h] + yn[s][1][h];
            sq += yn[s][0][h] * yn[s][0][h] + yn[s][1][h] * yn[s][1][h];
        }
        red[h] = sm; red[4 + h] = sq;
    }
    // wave(64) reduce -> lane 0 of each wave
#pragma unroll
    for (int j = 0; j < 8; ++j)
#pragma unroll
        for (int off = 32; off > 0; off >>= 1)
            red[j] += __shfl_down(red[j], off);
    const int wv = tid >> 6, ln = tid & 63;
    if (ln == 0) {
#pragma unroll
        for (int j = 0; j < 8; ++j) pb[wv][j] = red[j];
    }
    __syncthreads();                       // pb ready
    if (wv == 0) {
        // lanes 0-3: combine 4 waves, store block partial word ln = stats (2ln, 2ln+1)
        if (ln < 4) {
            float lo = pb[0][2 * ln]     + pb[1][2 * ln]     + pb[2][2 * ln]     + pb[3][2 * ln];
            float hi = pb[0][2 * ln + 1] + pb[1][2 * ln + 1] + pb[2][2 * ln + 1] + pb[3][2 * ln + 1];
            unsigned long long v = ((unsigned long long)__float_as_uint(hi) << 32)
                                 |  (unsigned long long)__float_as_uint(lo);
            __hip_atomic_store(&slots[((size_t)t * NBLK + blockIdx.x) * 4 + ln], v,
                               __ATOMIC_RELAXED, __HIP_MEMORY_SCOPE_AGENT);
        }
        // poll: lane ln watches words ln and ln+64 of this step's 128 words
        const unsigned long long* base = slots + (size_t)t * NBLK * 4;
        unsigned long long q0, q1;
        do {
            q0 = __hip_atomic_load(base + ln,      __ATOMIC_RELAXED, __HIP_MEMORY_SCOPE_AGENT);
            q1 = __hip_atomic_load(base + ln + 64, __ATOMIC_RELAXED, __HIP_MEMORY_SCOPE_AGENT);
        } while (!__all(q0 != SENT && q1 != SENT));
        // lane ln holds stat-pair (2w, 2w+1), w = ln&3, for blocks ln>>2 and (ln>>2)+16
        float slo = __uint_as_float((unsigned)q0) + __uint_as_float((unsigned)q1);
        float shi = __uint_as_float((unsigned)(q0 >> 32)) + __uint_as_float((unsigned)(q1 >> 32));
#pragma unroll
        for (int d = 4; d < 64; d <<= 1) {
            slo += __shfl_xor(slo, d);
            shi += __shfl_xor(shi, d);
        }
        if (ln < 4) { totl[2 * ln] = slo; totl[2 * ln + 1] = shi; }
    }
    __syncthreads();                       // totals visible to all waves
    float sm[8];
#pragma unroll
    for (int j = 0; j < 8; ++j) sm[j] = totl[j];
#pragma unroll
    for (int h = 0; h < HIDN; ++h) {
        float m  = sm[h] * INV_ROWS;
        float v  = fmaf(-m, m, sm[4 + h] * INV_ROWS);
        float is = rsqrtf(v + BN_EPS) * gm[h];
        float sh = bt[h] - m * is;
#pragma unroll
        for (int s = 0; s < SPT; ++s) {
            y[s][0][h] = fmaf(yn[s][0][h], is, sh);
            y[s][1][h] = fmaf(yn[s][1][h], is, sh);
        }
    }
}

__global__ __launch_bounds__(BLK, 1)
void ttbn_main(const float* __restrict__ x,  const float* __restrict__ wf,
               const float* __restrict__ wm, const float* __restrict__ wl,
               const float* __restrict__ gamma, const float* __restrict__ beta,
               float* __restrict__ out, unsigned long long* __restrict__ slots)
{
    __shared__ float pb[BLK / 64][8];
    __shared__ float totl[8];
    const int tid = threadIdx.x;

    float gm[HIDN], bt[HIDN];
#pragma unroll
    for (int h = 0; h < HIDN; ++h) { gm[h] = gamma[h]; bt[h] = beta[h]; }

    const float* xn[SPT];
    long nidx[SPT];
#pragma unroll
    for (int s = 0; s < SPT; ++s) {
        nidx[s] = (long)blockIdx.x * (BLK * SPT) + s * BLK + tid;
        xn[s]   = x + nidx[s] * (INB * NPIX);
    }

    /* 2-pixel groups (float2), double-buffered: xg2 prefetch is issued a full
       group (2 syncs, ~7us) ahead -> L3 latency never exposed. */
    float2 xg[SPT][INB], xg2[SPT][INB];
    float  y[SPT][CHN][HIDN];

    // ---- group 0: pixels 0,1 ----
#pragma unroll
    for (int s = 0; s < SPT; ++s)
#pragma unroll
        for (int i = 0; i < INB; ++i)
            xg[s][i] = *reinterpret_cast<const float2*>(xn[s] + i * NPIX);

#pragma unroll
    for (int s = 0; s < SPT; ++s)
#pragma unroll
        for (int c = 0; c < CHN; ++c)
#pragma unroll
            for (int h = 0; h < HIDN; ++h) {
                float acc = 0.f;
#pragma unroll
                for (int i = 0; i < INB; ++i)
                    acc = fmaf(xg[s][i].x, wf[i * (HIDN * CHN) + h * CHN + c], acc);
                y[s][c][h] = acc;
            }
    // prefetch group 1 (pixels 2,3) before the first sync
#pragma unroll
    for (int s = 0; s < SPT; ++s)
#pragma unroll
        for (int i = 0; i < INB; ++i)
            xg2[s][i] = *reinterpret_cast<const float2*>(xn[s] + i * NPIX + 2);
    {   // step t=0: pixel 1
        float xv[SPT][INB];
#pragma unroll
        for (int s = 0; s < SPT; ++s)
#pragma unroll
            for (int i = 0; i < INB; ++i) xv[s][i] = xg[s][i].y;
        mid_step(0, xv, y, wm, gm, bt, slots, pb, totl, tid);
    }

    // ---- groups 1..96: pixels 2g (t=2g-1), 2g+1 (t=2g) ----
#pragma unroll 1
    for (int g = 1; g < 97; ++g) {
#pragma unroll
        for (int s = 0; s < SPT; ++s)
#pragma unroll
            for (int i = 0; i < INB; ++i) xg[s][i] = xg2[s][i];
        // prefetch group g+1 (pixels 2g+2, 2g+3); hides under 2 syncs
#pragma unroll
        for (int s = 0; s < SPT; ++s)
#pragma unroll
            for (int i = 0; i < INB; ++i)
                xg2[s][i] = *reinterpret_cast<const float2*>(xn[s] + i * NPIX + 2 * (g + 1));
        {
            float xv[SPT][INB];
#pragma unroll
            for (int s = 0; s < SPT; ++s)
#pragma unroll
                for (int i = 0; i < INB; ++i) xv[s][i] = xg[s][i].x;
            mid_step(2 * g - 1, xv, y, wm, gm, bt, slots, pb, totl, tid);
        }
        {
            float xv[SPT][INB];
#pragma unroll
            for (int s = 0; s < SPT; ++s)
#pragma unroll
                for (int i = 0; i < INB; ++i) xv[s][i] = xg[s][i].y;
            mid_step(2 * g, xv, y, wm, gm, bt, slots, pb, totl, tid);
        }
    }

    // ---- group 97: pixels 194 (t=193), 195 (final) ----
#pragma unroll
    for (int s = 0; s < SPT; ++s)
#pragma unroll
        for (int i = 0; i < INB; ++i) xg[s][i] = xg2[s][i];
    {
        float xv[SPT][INB];
#pragma unroll
        for (int s = 0; s < SPT; ++s)
#pragma unroll
            for (int i = 0; i < INB; ++i) xv[s][i] = xg[s][i].x;
        mid_step(193, xv, y, wm, gm, bt, slots, pb, totl, tid);
    }
    // pixel 195: out[n,0,c,o] = sum_{r,i} y[c][r]*x_i*wl[r,i,o,c]
#pragma unroll
    for (int s = 0; s < SPT; ++s) {
        float xv[INB];
#pragma unroll
        for (int i = 0; i < INB; ++i) xv[i] = xg[s][i].y;
        float o0[OUTD], o1[OUTD];
#pragma unroll
        for (int od = 0; od < OUTD; ++od) { o0[od] = 0.f; o1[od] = 0.f; }
#pragma unroll
        for (int r = 0; r < HIDN; ++r)
#pragma unroll
            for (int i = 0; i < INB; ++i) {
                float p0 = y[s][0][r] * xv[i];
                float p1 = y[s][1][r] * xv[i];
                const float* wri = wl + r * (INB * OUTD * CHN) + i * (OUTD * CHN);
#pragma unroll
                for (int od = 0; od < OUTD; ++od) {
                    o0[od] = fmaf(p0, wri[od * CHN + 0], o0[od]);
                    o1[od] = fmaf(p1, wri[od * CHN + 1], o1[od]);
                }
            }
        float tmp[20];
#pragma unroll
        for (int od = 0; od < OUTD; ++od) { tmp[od] = o0[od]; tmp[10 + od] = o1[od]; }
        float4* o4 = reinterpret_cast<float4*>(out + nidx[s] * (CHN * OUTD));
#pragma unroll
        for (int q = 0; q < 5; ++q)
            o4[q] = make_float4(tmp[q * 4], tmp[q * 4 + 1], tmp[q * 4 + 2], tmp[q * 4 + 3]);
    }
}

extern "C" void kernel_launch(void* const* d_in, const int* in_sizes, int n_in,
                              void* d_out, int out_size, void* d_ws, size_t ws_size,
                              hipStream_t stream) {
    const float* x     = (const float*)d_in[0];
    const float* wf    = (const float*)d_in[1];
    const float* wm    = (const float*)d_in[2];
    const float* wl    = (const float*)d_in[3];
    const float* gamma = (const float*)d_in[4];
    const float* beta  = (const float*)d_in[5];
    float*       out   = (float*)d_out;
    unsigned long long* slots = (unsigned long long*)d_ws;

    // sentinel-fill the slot array (0xFF bytes == SENT); stream-ordered before kernel
    hipMemsetAsync(d_ws, 0xFF, WS_BYTES, stream);

    void* args[] = { &x, &wf, &wm, &wl, &gamma, &beta, &out, &slots };
    hipLaunchCooperativeKernel((void*)ttbn_main, dim3(NBLK), dim3(BLK),
                               args, 0, stream);
}

// Round 15
// 795.515 us; speedup vs baseline: 3.6920x; 1.3841x over previous
//
#include <hip/hip_runtime.h>

#define NSAMP 32768
#define INB   4
#define HIDN  4
#define CHN   2
#define OUTD  10
#define NPIX  196
#define NMID  194
#define BLK   512
#define NBLK  (NSAMP / BLK)            /* 64 blocks == wave width, 1 sample/thread */
#define INV_ROWS 1.52587890625e-05f    /* 1 / (N*CH) = 1/65536 */
#define BN_EPS 1e-5f
#define SENT  0xFFFFFFFFFFFFFFFFull    /* NaN-pair sentinel, unreachable by finite math */
/* ws: slots[NMID][NBLK][4] u64 — R8's fused store/poll barrier: only wave 0
   touches global in the sync; lane l polls block l's 32B slot; detection ==
   data delivery. Pipelining: the step-(t+1) contraction matrix M (x ⊗ w,
   independent of BN stats) is computed INSIDE step t's poll window, so the
   inter-sync critical chain is only BN-apply + y·M + reduce + store. */
#define WS_BYTES ((size_t)NMID * NBLK * 4 * sizeof(unsigned long long))

__device__ __forceinline__ float xcomp(const float4& v, int j) {
    return j == 0 ? v.x : j == 1 ? v.y : j == 2 ? v.z : v.w;
}

__global__ __launch_bounds__(BLK, 1)
void ttbn_main(const float* __restrict__ x,  const float* __restrict__ wf,
               const float* __restrict__ wm, const float* __restrict__ wl,
               const float* __restrict__ gamma, const float* __restrict__ beta,
               float* __restrict__ out, unsigned long long* __restrict__ slots)
{
    __shared__ float pb[BLK / 64][8];
    __shared__ float totl[8];
    const int tid = threadIdx.x;
    const int ln  = tid & 63, wv = tid >> 6;
    const long n  = (long)blockIdx.x * BLK + tid;

    float gm[HIDN], bt[HIDN];
#pragma unroll
    for (int h = 0; h < HIDN; ++h) { gm[h] = gamma[h]; bt[h] = beta[h]; }

    const float* xrow = x + n * (INB * NPIX);

    float4 xq[INB];               // current 4-pixel group per bond
#pragma unroll
    for (int i = 0; i < INB; ++i)
        xq[i] = *reinterpret_cast<const float4*>(xrow + i * NPIX);   // pixels 0-3

    // ---- y init from pixel 0 (no BN) ----
    float y[CHN][HIDN];
#pragma unroll
    for (int c = 0; c < CHN; ++c)
#pragma unroll
        for (int h = 0; h < HIDN; ++h) {
            float acc = 0.f;
#pragma unroll
            for (int i = 0; i < INB; ++i)
                acc = fmaf(xq[i].x, wf[i * (HIDN * CHN) + h * CHN + c], acc);
            y[c][h] = acc;
        }
    // ---- M_0 from pixel 1 ----
    float M[CHN][HIDN][HIDN];
#pragma unroll
    for (int c = 0; c < CHN; ++c)
#pragma unroll
        for (int r = 0; r < HIDN; ++r)
#pragma unroll
            for (int h = 0; h < HIDN; ++h) {
                float m = 0.f;
#pragma unroll
                for (int i = 0; i < INB; ++i)
                    m = fmaf(xq[i].y, wm[(r * 16 + i * 4 + h) * 2 + c], m);
                M[c][r][h] = m;
            }

    float yn[CHN][HIDN];

#pragma unroll 1
    for (int t = 0; t < NMID; ++t) {
        // ---- critical chain: yn = y·M (32 FMA) ----
#pragma unroll
        for (int c = 0; c < CHN; ++c)
#pragma unroll
            for (int h = 0; h < HIDN; ++h) {
                float acc = 0.f;
#pragma unroll
                for (int r = 0; r < HIDN; ++r)
                    acc = fmaf(y[c][r], M[c][r][h], acc);
                yn[c][h] = acc;
            }
        // ---- stats partials + wave reduce ----
        float red[8];
#pragma unroll
        for (int h = 0; h < HIDN; ++h) {
            red[h]     = yn[0][h] + yn[1][h];
            red[4 + h] = yn[0][h] * yn[0][h] + yn[1][h] * yn[1][h];
        }
#pragma unroll
        for (int j = 0; j < 8; ++j)
#pragma unroll
            for (int off = 32; off > 0; off >>= 1)
                red[j] += __shfl_down(red[j], off);
        if (ln == 0) {
#pragma unroll
            for (int j = 0; j < 8; ++j) pb[wv][j] = red[j];
        }
        __syncthreads();
        // ---- wave0 lanes 0-3: combine 8 waves, issue block-partial store ----
        if (wv == 0 && ln < 4) {
            float lo = 0.f, hi = 0.f;
#pragma unroll
            for (int w = 0; w < 8; ++w) {
                lo += pb[w][2 * ln];
                hi += pb[w][2 * ln + 1];
            }
            unsigned long long v = ((unsigned long long)__float_as_uint(hi) << 32)
                                 |  (unsigned long long)__float_as_uint(lo);
            __hip_atomic_store(&slots[((size_t)t * NBLK + blockIdx.x) * 4 + ln], v,
                               __ATOMIC_RELAXED, __HIP_MEMORY_SCOPE_AGENT);
        }
        // ---- poll shadow: next-step M (and x group) — independent of stats.
        //      Waves 1-7: runs while wave0 polls. Wave0: fits under commit. ----
        if (t < NMID - 1) {
            const int q = t + 2;            // pixel feeding M_{t+1}
            if ((q & 3) == 0) {
#pragma unroll
                for (int i = 0; i < INB; ++i)
                    xq[i] = *reinterpret_cast<const float4*>(xrow + i * NPIX + q);
            }
            float xv[INB];
#pragma unroll
            for (int i = 0; i < INB; ++i) xv[i] = xcomp(xq[i], q & 3);
            const float* w1 = wm + (size_t)(t + 1) * 128;
#pragma unroll
            for (int c = 0; c < CHN; ++c)
#pragma unroll
                for (int r = 0; r < HIDN; ++r)
#pragma unroll
                    for (int h = 0; h < HIDN; ++h) {
                        float m = 0.f;
#pragma unroll
                        for (int i = 0; i < INB; ++i)
                            m = fmaf(xv[i], w1[(r * 16 + i * 4 + h) * 2 + c], m);
                        M[c][r][h] = m;
                    }
        }
        // ---- wave0: fused sentinel poll over all 64 block-slots ----
        if (wv == 0) {
            const unsigned long long* ps = &slots[((size_t)t * NBLK + ln) * 4];
            unsigned long long q0, q1, q2, q3;
            do {
                q0 = __hip_atomic_load(&ps[0], __ATOMIC_RELAXED, __HIP_MEMORY_SCOPE_AGENT);
                q1 = __hip_atomic_load(&ps[1], __ATOMIC_RELAXED, __HIP_MEMORY_SCOPE_AGENT);
                q2 = __hip_atomic_load(&ps[2], __ATOMIC_RELAXED, __HIP_MEMORY_SCOPE_AGENT);
                q3 = __hip_atomic_load(&ps[3], __ATOMIC_RELAXED, __HIP_MEMORY_SCOPE_AGENT);
            } while (!__all(q0 != SENT && q1 != SENT && q2 != SENT && q3 != SENT));
            float sm[8];
            sm[0] = __uint_as_float((unsigned)q0); sm[1] = __uint_as_float((unsigned)(q0 >> 32));
            sm[2] = __uint_as_float((unsigned)q1); sm[3] = __uint_as_float((unsigned)(q1 >> 32));
            sm[4] = __uint_as_float((unsigned)q2); sm[5] = __uint_as_float((unsigned)(q2 >> 32));
            sm[6] = __uint_as_float((unsigned)q3); sm[7] = __uint_as_float((unsigned)(q3 >> 32));
#pragma unroll
            for (int j = 0; j < 8; ++j)
#pragma unroll
                for (int off = 1; off < 64; off <<= 1)
                    sm[j] += __shfl_xor(sm[j], off);
            if (ln < 8) totl[ln] = sm[ln];
        }
        __syncthreads();
        // ---- BN apply ----
        float s0 = totl[0], s1 = totl[1], s2 = totl[2], s3 = totl[3];
        float t0 = totl[4], t1 = totl[5], t2 = totl[6], t3 = totl[7];
        float smv[8] = {s0, s1, s2, s3, t0, t1, t2, t3};
#pragma unroll
        for (int h = 0; h < HIDN; ++h) {
            float m  = smv[h] * INV_ROWS;
            float v  = fmaf(-m, m, smv[4 + h] * INV_ROWS);
            float is = rsqrtf(v + BN_EPS) * gm[h];
            float sh = bt[h] - m * is;
            y[0][h] = fmaf(yn[0][h], is, sh);
            y[1][h] = fmaf(yn[1][h], is, sh);
        }
    }

    // ---- final step: pixel 195 (= xq comp 3, group 48) with wl, no BN ----
    {
        float xv[INB];
#pragma unroll
        for (int i = 0; i < INB; ++i) xv[i] = xq[i].w;
        float o0[OUTD], o1[OUTD];
#pragma unroll
        for (int od = 0; od < OUTD; ++od) { o0[od] = 0.f; o1[od] = 0.f; }
#pragma unroll
        for (int r = 0; r < HIDN; ++r)
#pragma unroll
            for (int i = 0; i < INB; ++i) {
                float p0 = y[0][r] * xv[i];
                float p1 = y[1][r] * xv[i];
                const float* wri = wl + r * (INB * OUTD * CHN) + i * (OUTD * CHN);
#pragma unroll
                for (int od = 0; od < OUTD; ++od) {
                    o0[od] = fmaf(p0, wri[od * CHN + 0], o0[od]);
                    o1[od] = fmaf(p1, wri[od * CHN + 1], o1[od]);
                }
            }
        float tmp[20];
#pragma unroll
        for (int od = 0; od < OUTD; ++od) { tmp[od] = o0[od]; tmp[10 + od] = o1[od]; }
        float4* o4 = reinterpret_cast<float4*>(out + n * (CHN * OUTD));
#pragma unroll
        for (int q = 0; q < 5; ++q)
            o4[q] = make_float4(tmp[q * 4], tmp[q * 4 + 1], tmp[q * 4 + 2], tmp[q * 4 + 3]);
    }
}

extern "C" void kernel_launch(void* const* d_in, const int* in_sizes, int n_in,
                              void* d_out, int out_size, void* d_ws, size_t ws_size,
                              hipStream_t stream) {
    const float* x     = (const float*)d_in[0];
    const float* wf    = (const float*)d_in[1];
    const float* wm    = (const float*)d_in[2];
    const float* wl    = (const float*)d_in[3];
    const float* gamma = (const float*)d_in[4];
    const float* beta  = (const float*)d_in[5];
    float*       out   = (float*)d_out;
    unsigned long long* slots = (unsigned long long*)d_ws;

    // sentinel-fill the slot array (0xFF bytes == SENT); stream-ordered before kernel
    hipMemsetAsync(d_ws, 0xFF, WS_BYTES, stream);

    void* args[] = { &x, &wf, &wm, &wl, &gamma, &beta, &out, &slots };
    hipLaunchCooperativeKernel((void*)ttbn_main, dim3(NBLK), dim3(BLK),
                               args, 0, stream);
}